// Round 1
// baseline (266.860 us; speedup 1.0000x reference)
//
#include <hip/hip_runtime.h>
#include <math.h>

#define IN_DIM 128
#define OUT_DIM 128
#define HEADS 4
#define HEAD_DIM 32

__device__ __forceinline__ float lrelu(float v) { return v >= 0.f ? v : 0.2f * v; }

// ---------------- GEMM: Wx[n][j] = sum_k x[n][k] * W[j][k] ----------------
// Block: 64 nodes x 64 output dims (blockIdx.y selects dim half).
// LDS: W half (64x128, stride 132) + x tile transposed (128x64, stride 68) = 67KB -> 2 blocks/CU.
__global__ __launch_bounds__(256, 2) void gemm_kernel(const float* __restrict__ x,
                                                      const float* __restrict__ W,
                                                      float* __restrict__ Wx, int n) {
    __shared__ float Ws[64 * 132];
    __shared__ float xs[128 * 68];
    const int t = threadIdx.x;
    const int nb = blockIdx.x, jh = blockIdx.y;
    const int node_base = nb * 64;

    // Stage W half: 64 rows x 128 cols
    const float* Wg = W + (size_t)jh * 64 * 128;
#pragma unroll
    for (int p = 0; p < 8; ++p) {
        int idx = (p * 256 + t) * 4;
        int j = idx >> 7, k = idx & 127;
        float4 v = *(const float4*)(Wg + idx);
        *(float4*)(&Ws[j * 132 + k]) = v;
    }
    // Stage x tile transposed: xs[k][nn] = x[node_base+nn][k]
    {
        int k0 = (t >> 3) * 4;
#pragma unroll
        for (int p = 0; p < 8; ++p) {
            int nn = (t & 7) + 8 * p;
            int gn = node_base + nn;
            if (gn >= n) gn = n - 1;
            float4 v = *(const float4*)(x + (size_t)gn * 128 + k0);
            xs[(k0 + 0) * 68 + nn] = v.x;
            xs[(k0 + 1) * 68 + nn] = v.y;
            xs[(k0 + 2) * 68 + nn] = v.z;
            xs[(k0 + 3) * 68 + nn] = v.w;
        }
    }
    __syncthreads();

    const int ng = t & 15;        // node group: nodes 4*ng .. 4*ng+3
    const int dg = t >> 4;        // dim group: dims dg, dg+16, dg+32, dg+48
    float acc[4][4] = {{0.f}};
#pragma unroll 8
    for (int k = 0; k < 128; ++k) {
        float4 a = *(const float4*)(&xs[k * 68 + 4 * ng]);
        float b0 = Ws[(dg + 0) * 132 + k];
        float b1 = Ws[(dg + 16) * 132 + k];
        float b2 = Ws[(dg + 32) * 132 + k];
        float b3 = Ws[(dg + 48) * 132 + k];
        acc[0][0] += a.x * b0; acc[0][1] += a.x * b1; acc[0][2] += a.x * b2; acc[0][3] += a.x * b3;
        acc[1][0] += a.y * b0; acc[1][1] += a.y * b1; acc[1][2] += a.y * b2; acc[1][3] += a.y * b3;
        acc[2][0] += a.z * b0; acc[2][1] += a.z * b1; acc[2][2] += a.z * b2; acc[2][3] += a.z * b3;
        acc[3][0] += a.w * b0; acc[3][1] += a.w * b1; acc[3][2] += a.w * b2; acc[3][3] += a.w * b3;
    }
#pragma unroll
    for (int a = 0; a < 4; ++a) {
        int gn = node_base + 4 * ng + a;
        if (gn < n) {
            float* dst = Wx + (size_t)gn * 128 + jh * 64 + dg;
            dst[0] = acc[a][0];
            dst[16] = acc[a][1];
            dst[32] = acc[a][2];
            dst[48] = acc[a][3];
        }
    }
}

// ---------------- per-node logits: s_src[n][h], s_dst[n][h] ----------------
__global__ __launch_bounds__(256) void s_kernel(const float* __restrict__ Wx,
                                                const float* __restrict__ aw,
                                                float* __restrict__ s_src,
                                                float* __restrict__ s_dst, int n) {
    int g = blockIdx.x * 256 + threadIdx.x;
    int node = g >> 2, h = g & 3;
    if (node >= n) return;
    const float4* row = (const float4*)(Wx + (size_t)node * 128 + h * 32);
    const float4* as = (const float4*)(aw);
    const float4* ad = (const float4*)(aw + 32);
    float ss = 0.f, sd = 0.f;
#pragma unroll
    for (int j = 0; j < 8; ++j) {
        float4 v = row[j], a1 = as[j], a2 = ad[j];
        ss += v.x * a1.x + v.y * a1.y + v.z * a1.z + v.w * a1.w;
        sd += v.x * a2.x + v.y * a2.y + v.z * a2.z + v.w * a2.w;
    }
    s_src[g] = ss;
    s_dst[g] = sd;
}

// ---------------- histogram of dst ----------------
__global__ __launch_bounds__(256) void hist_kernel(const int* __restrict__ ei, int* __restrict__ hist, int E) {
    int e = blockIdx.x * 256 + threadIdx.x;
    if (e < E) atomicAdd(&hist[ei[E + e]], 1);
}

// ---------------- 2-level exclusive scan ----------------
__global__ __launch_bounds__(256) void scan1_kernel(const int* __restrict__ hist, int* __restrict__ part,
                                                    int* __restrict__ bsums, int n) {
    __shared__ int sm[256];
    int t = threadIdx.x, g = blockIdx.x * 256 + t;
    int v = (g < n) ? hist[g] : 0;
    sm[t] = v;
    __syncthreads();
    for (int off = 1; off < 256; off <<= 1) {
        int y = (t >= off) ? sm[t - off] : 0;
        __syncthreads();
        sm[t] += y;
        __syncthreads();
    }
    if (g < n) part[g] = sm[t] - v;       // exclusive within block
    if (t == 255) bsums[blockIdx.x] = sm[t];
}

__global__ __launch_bounds__(256) void scan2_kernel(int* __restrict__ bsums, int nb) {
    __shared__ int sm[256];
    int t = threadIdx.x;
    int v = (t < nb) ? bsums[t] : 0;
    sm[t] = v;
    __syncthreads();
    for (int off = 1; off < 256; off <<= 1) {
        int y = (t >= off) ? sm[t - off] : 0;
        __syncthreads();
        sm[t] += y;
        __syncthreads();
    }
    bsums[t] = sm[t] - v;                 // exclusive block offsets
}

__global__ __launch_bounds__(256) void scan3_kernel(int* __restrict__ offs, const int* __restrict__ bsums,
                                                    int* __restrict__ cursor, int n, int E) {
    int g = blockIdx.x * 256 + threadIdx.x;
    if (g < n) {
        int o = offs[g] + bsums[g >> 8];
        offs[g] = o;
        cursor[g] = o;
    }
    if (g == 0) offs[n] = E;
}

// ---------------- edge scatter into CSR + exp weights ----------------
__global__ __launch_bounds__(256) void scatter_kernel(const int* __restrict__ ei,
                                                      const float* __restrict__ s_src,
                                                      const float* __restrict__ s_dst,
                                                      int* __restrict__ cursor,
                                                      int* __restrict__ csr_src,
                                                      float4* __restrict__ e_w, int E) {
    int e = blockIdx.x * 256 + threadIdx.x;
    if (e >= E) return;
    int src = ei[e], dst = ei[E + e];
    float4 ss = *(const float4*)(s_src + (size_t)src * 4);
    float4 sd = *(const float4*)(s_dst + (size_t)dst * 4);
    float4 w;
    w.x = __expf(lrelu(ss.x + sd.x));     // no max-shift: |logit| <= ~6, exp safe in fp32
    w.y = __expf(lrelu(ss.y + sd.y));
    w.z = __expf(lrelu(ss.z + sd.z));
    w.w = __expf(lrelu(ss.w + sd.w));
    int pos = atomicAdd(&cursor[dst], 1);
    csr_src[pos] = src;
    e_w[pos] = w;
}

// ---------------- per-node accumulate + softmax-normalize + ELU ----------------
// One wave (64 lanes) per node; 4 waves per block.
__global__ __launch_bounds__(256) void accum_kernel(const int* __restrict__ offs,
                                                    const int* __restrict__ csr_src,
                                                    const float* __restrict__ e_w,
                                                    const float* __restrict__ Wx,
                                                    float* __restrict__ out, int n) {
    int wid = threadIdx.x >> 6, lane = threadIdx.x & 63;
    int node = blockIdx.x * 4 + wid;
    if (node >= n) return;
    int start = offs[node], end = offs[node + 1];
    int deg = end - start;

    // Pass A: denominator per head (local, no atomics)
    float4 dsum = {0.f, 0.f, 0.f, 0.f};
    for (int i = lane; i < deg; i += 64) {
        float4 w = *(const float4*)(e_w + (size_t)(start + i) * 4);
        dsum.x += w.x; dsum.y += w.y; dsum.z += w.z; dsum.w += w.w;
    }
#pragma unroll
    for (int m = 32; m >= 1; m >>= 1) {
        dsum.x += __shfl_xor(dsum.x, m, 64);
        dsum.y += __shfl_xor(dsum.y, m, 64);
        dsum.z += __shfl_xor(dsum.z, m, 64);
        dsum.w += __shfl_xor(dsum.w, m, 64);
    }
    float inv0 = 1.f / (dsum.x + 1e-8f);
    float inv1 = 1.f / (dsum.y + 1e-8f);
    float inv2 = 1.f / (dsum.z + 1e-8f);
    float inv3 = 1.f / (dsum.w + 1e-8f);

    // Pass B: 2 edges per wave-iteration; lanes 0-31 even edges, 32-63 odd edges.
    int q = lane & 31;            // dim quad: dims 4q..4q+3
    int half = lane >> 5;
    int h = q >> 3;               // head of this dim quad
    float invh = (h == 0) ? inv0 : (h == 1) ? inv1 : (h == 2) ? inv2 : inv3;
    float4 acc = {0.f, 0.f, 0.f, 0.f};
    for (int i = half; i < deg; i += 2) {
        int idx = start + i;
        int src = csr_src[idx];
        float alpha = e_w[(size_t)idx * 4 + h] * invh;
        float4 v = *(const float4*)(Wx + (size_t)src * 128 + q * 4);
        acc.x += alpha * v.x; acc.y += alpha * v.y; acc.z += alpha * v.z; acc.w += alpha * v.w;
    }
    acc.x += __shfl_down(acc.x, 32, 64);
    acc.y += __shfl_down(acc.y, 32, 64);
    acc.z += __shfl_down(acc.z, 32, 64);
    acc.w += __shfl_down(acc.w, 32, 64);
    if (lane < 32) {
        float4 o;
        o.x = acc.x > 0.f ? acc.x : expm1f(acc.x);
        o.y = acc.y > 0.f ? acc.y : expm1f(acc.y);
        o.z = acc.z > 0.f ? acc.z : expm1f(acc.z);
        o.w = acc.w > 0.f ? acc.w : expm1f(acc.w);
        *(float4*)(out + (size_t)node * 128 + q * 4) = o;
    }
}

extern "C" void kernel_launch(void* const* d_in, const int* in_sizes, int n_in,
                              void* d_out, int out_size, void* d_ws, size_t ws_size,
                              hipStream_t stream) {
    const float* x = (const float*)d_in[0];
    const int* ei = (const int*)d_in[1];
    const float* W = (const float*)d_in[2];
    const float* aw = (const float*)d_in[3];
    float* out = (float*)d_out;
    const int n = in_sizes[0] / IN_DIM;    // 50000
    const int E = in_sizes[1] / 2;         // 800000

    char* ws = (char*)d_ws;
    size_t off = 0;
    float* Wx = (float*)(ws + off);      off += (size_t)n * OUT_DIM * 4;   // 25.6 MB
    float* s_src = (float*)(ws + off);   off += (size_t)n * HEADS * 4;     // 800 KB
    float* s_dst = (float*)(ws + off);   off += (size_t)n * HEADS * 4;     // 800 KB
    int* hist = (int*)(ws + off);        off += (size_t)n * 4;             // 200 KB
    int* offs = (int*)(ws + off);        off += ((size_t)n + 64) * 4;      // 200 KB
    int* cursor = (int*)(ws + off);      off += (size_t)n * 4;             // 200 KB
    int* bsums = (int*)(ws + off);       off += 1024;
    int* csr_src = (int*)(ws + off);     off += (size_t)E * 4;             // 3.2 MB
    float* e_w = (float*)(ws + off);     off += (size_t)E * HEADS * 4;     // 12.8 MB

    const int nblocks64 = (n + 63) / 64;
    const int sblocks = (n * HEADS + 255) / 256;
    const int eblocks = (E + 255) / 256;
    const int scanblocks = (n + 255) / 256;   // 196 <= 256, fits level-2 single block

    hipMemsetAsync(hist, 0, (size_t)n * 4, stream);
    gemm_kernel<<<dim3(nblocks64, 2), 256, 0, stream>>>(x, W, Wx, n);
    s_kernel<<<sblocks, 256, 0, stream>>>(Wx, aw, s_src, s_dst, n);
    hist_kernel<<<eblocks, 256, 0, stream>>>(ei, hist, E);
    scan1_kernel<<<scanblocks, 256, 0, stream>>>(hist, offs, bsums, n);
    scan2_kernel<<<1, 256, 0, stream>>>(bsums, scanblocks);
    scan3_kernel<<<scanblocks, 256, 0, stream>>>(offs, bsums, cursor, n, E);
    scatter_kernel<<<eblocks, 256, 0, stream>>>(ei, s_src, s_dst, cursor, csr_src, (float4*)e_w, E);
    accum_kernel<<<(n + 3) / 4, 256, 0, stream>>>(offs, csr_src, e_w, Wx, out, n);
}